// Round 2
// 825.391 us; speedup vs baseline: 1.1820x; 1.1820x over previous
//
#include <hip/hip_runtime.h>
#include <hip/hip_bf16.h>

typedef __bf16 bf16x8 __attribute__((ext_vector_type(8)));
typedef float  f32x4  __attribute__((ext_vector_type(4)));

#define MFMA(a, b, c) __builtin_amdgcn_mfma_f32_16x16x32_bf16((a), (b), (c), 0, 0, 0)

typedef __attribute__((address_space(1))) void* as1_vp;
typedef __attribute__((address_space(3))) void* as3_vp;

__device__ __forceinline__ void g2lds16(const void* g, void* lds) {
  __builtin_amdgcn_global_load_lds((as1_vp)(unsigned long long)g,
                                   (as3_vp)(unsigned int)(unsigned long long)lds,
                                   16, 0, 0);
}

__device__ __forceinline__ unsigned short bfbits(float x) {
  return __builtin_bit_cast(unsigned short, __float2bfloat16(x));
}

// ---------------------------------------------------------------- convert
__global__ void cvt_f32_bf16(const float* __restrict__ in,
                             __hip_bfloat16* __restrict__ out, int n4) {
  int i = blockIdx.x * blockDim.x + threadIdx.x;
  if (i >= n4) return;
  float4 v = ((const float4*)in)[i];
  ushort4 u;
  u.x = bfbits(v.x); u.y = bfbits(v.y); u.z = bfbits(v.z); u.w = bfbits(v.w);
  ((ushort4*)out)[i] = u;
}

// ---------------------------------------------------------------- bias concat (fp32)
__global__ void concat_bias(const float* __restrict__ bq, const float* __restrict__ bk,
                            const float* __restrict__ bv, float* __restrict__ out) {
  int i = blockIdx.x * 256 + threadIdx.x;  // 6144 total
  float v = (i < 4096) ? bq[i] : ((i < 5120) ? bk[i - 4096] : bv[i - 5120]);
  out[i] = v;
}

// ---------------------------------------------------------------- rope (in-place, pitch-aware)
__global__ void rope_inplace(__hip_bfloat16* __restrict__ x, const float* __restrict__ fc,
                             const int* __restrict__ startpos, int pitch, int wshift,
                             long npairs) {
  long i = (long)blockIdx.x * blockDim.x + threadIdx.x;
  if (i >= npairs) return;
  int  wi    = (int)(i & ((1 << wshift) - 1));
  long token = i >> wshift;
  int  s  = (int)(token & 2047);
  int  j  = wi & 63;
  int  sp = startpos[0] + s;
  float c  = fc[(sp << 7) + (j << 1)];
  float sn = fc[(sp << 7) + (j << 1) + 1];
  long base = token * pitch + wi * 2;
  float xr = __bfloat162float(x[base]);
  float xi = __bfloat162float(x[base + 1]);
  x[base]     = __float2bfloat16(xr * c - xi * sn);
  x[base + 1] = __float2bfloat16(xr * sn + xi * c);
}

// ---------------------------------------------------------------- V transpose
__global__ void transpose_v(const __hip_bfloat16* __restrict__ QKV,
                            __hip_bfloat16* __restrict__ VT) {
  __shared__ __hip_bfloat16 tile[32][33];
  int z = blockIdx.z, b = z >> 3, kvh = z & 7;
  int s0 = blockIdx.x * 32, h0 = blockIdx.y * 32;
  int tx = threadIdx.x, ty = threadIdx.y;
#pragma unroll
  for (int ry = ty; ry < 32; ry += 8)
    tile[ry][tx] =
        QKV[(long)(b * 2048 + s0 + ry) * 6144 + 5120 + kvh * 128 + h0 + tx];
  __syncthreads();
#pragma unroll
  for (int ry = ty; ry < 32; ry += 8)
    VT[((long)z * 128 + h0 + ry) * 2048 + s0 + tx] = tile[tx][ry];
}

// ---------------------------------------------------------------- GEMM  C = A * W^T + bias
// 256x256 tile, BK=64, 512 thr = 8 waves (2M x 4N), 8-phase schedule with
// counted vmcnt (T3+T4), 2-bit LDS chunk swizzle (T2), setprio around MFMA (T5).
// LDS 128KB: [buf(2)][ A: half0 16K | half1 16K | B: half0 16K | half1 16K ]
// Each half-tile = [ksub(2)][128 rows][64B], chunk c stored at c ^ ((row>>1)&3).
#define BAR()  __builtin_amdgcn_s_barrier()
#define SB0()  __builtin_amdgcn_sched_barrier(0)
#define LGK0() do { asm volatile("s_waitcnt lgkmcnt(0)" ::: "memory"); \
                    __builtin_amdgcn_sched_barrier(0); } while (0)
#define VMC4() asm volatile("s_waitcnt vmcnt(4)" ::: "memory")
#define VMC0() asm volatile("s_waitcnt vmcnt(0)" ::: "memory")
#define PRI1() __builtin_amdgcn_s_setprio(1)
#define PRI0() __builtin_amdgcn_s_setprio(0)

template <int OUT_F32>
__global__ void __launch_bounds__(512, 2)
gemm256_bt(const __hip_bfloat16* __restrict__ A,
           const __hip_bfloat16* __restrict__ W,
           const float* __restrict__ bias,
           void* __restrict__ Cout, int M, int N, int K) {
  __shared__ __align__(16) char smem[131072];
  (void)M;
  const int t = threadIdx.x, w = t >> 6, l = t & 63, quad = l >> 4, lan = l & 15;
  const int wm = w >> 2, wn = w & 3;

  // bijective XCD swizzle (8 XCDs), m204 form
  const int nwg = gridDim.x;
  const int xcd = blockIdx.x & 7, lid = blockIdx.x >> 3;
  const int qq = nwg >> 3, rr = nwg & 7;
  const int wg = (xcd < rr ? xcd * (qq + 1) : rr * (qq + 1) + (xcd - rr) * qq) + lid;
  const int ntn = N >> 8;
  const int bm = (wg / ntn) << 8, bn = (wg % ntn) << 8;

  // ---- staging source pointers (per-thread; chunk pre-swizzled so LDS dest is linear)
  // thread t covers row r=t>>2 (within 128-row half), chunk c=t&3; src chunk = c ^ ((r>>1)&3)
  const int csrc = ((t & 3) ^ ((t >> 3) & 3)) << 4;
  const char* aS0 = (const char*)(A + (long)(bm + (t >> 2)) * K) + csrc;
  const char* aS1 = aS0 + (long)K * 256;  // +128 rows
  const char* bS0 = (const char*)(W + (long)(bn + (t >> 2)) * K) + csrc;
  const char* bS1 = bS0 + (long)K * 256;
  // wave-uniform LDS staging dests (hw appends lane*16)
  char* dA0 = smem + (w << 10);
  char* dA1 = smem + 16384 + (w << 10);
  char* dB0 = smem + 32768 + (w << 10);
  char* dB1 = smem + 49152 + (w << 10);

#define STG(src, dst, kt, bb)                                    \
  g2lds16((src) + (kt) * 128, (dst) + (bb) * 65536);             \
  g2lds16((src) + (kt) * 128 + 64, (dst) + (bb) * 65536 + 8192);

  // ---- fragment read bases (per-lane), same swizzle on read side
  const int rsw = (quad ^ ((lan >> 1) & 3)) << 4;
  const char* aR = smem + wm * 16384 + (lan << 6) + rsw;
  const char* bR = smem + 32768 + (wn >> 1) * 16384 + ((((wn & 1) << 6) + lan) << 6) + rsw;

  f32x4 acc[8][4] = {};
  bf16x8 fA[4][2], fB0[2][2], fB1[2][2];

#define RD_A(mb, bb)                                                          \
  _Pragma("unroll") for (int mm = 0; mm < 4; ++mm)                            \
  _Pragma("unroll") for (int j = 0; j < 2; ++j)                               \
    fA[mm][j] = *(const bf16x8*)(aR + (bb) * 65536 + ((mb) + mm) * 1024 + j * 8192);
#define RD_B(arr, nb, bb)                                                     \
  _Pragma("unroll") for (int nn = 0; nn < 2; ++nn)                            \
  _Pragma("unroll") for (int j = 0; j < 2; ++j)                               \
    arr[nn][j] = *(const bf16x8*)(bR + (bb) * 65536 + ((nb) + nn) * 1024 + j * 8192);
#define MM16(mb, arr, nb)                                                     \
  _Pragma("unroll") for (int mm = 0; mm < 4; ++mm)                            \
  _Pragma("unroll") for (int nn = 0; nn < 2; ++nn)                            \
  _Pragma("unroll") for (int j = 0; j < 2; ++j)                               \
    acc[(mb) + mm][(nb) + nn] = MFMA(fA[mm][j], arr[nn][j], acc[(mb) + mm][(nb) + nn]);

  // ---- prologue: tile0 (buf0) fully, then tile1 B-halves (buf1); keep last 4 loads in flight
  STG(aS0, dA0, 0, 0); STG(aS1, dA1, 0, 0);
  STG(bS0, dB0, 0, 0); STG(bS1, dB1, 0, 0);
  STG(bS0, dB0, 1, 1); STG(bS1, dB1, 1, 1);
  VMC4();
  BAR();

  const int NT = K >> 6;
  // steady state per iter i (tiles 2i in buf0, 2i+1 in buf1):
  //  ph1: Ah0(2i+1)->buf1   ph2: Ah1(2i+1)->buf1   ph3: Bh0(2i+2)->buf0
  //  ph4: Bh1(2i+2)->buf0 +vmcnt(4)                ph5: Ah0(2i+2)->buf0
  //  ph6: Ah1(2i+2)->buf0   ph7: Bh0(2i+3)->buf1   ph8: Bh1(2i+3)->buf1 +vmcnt(4)
  // region-free proof: B reads of a tile finish ph2/ph6 (lgkmcnt0), A reads ph3/ph7.
  for (int i = 0; i < (NT >> 1) - 1; ++i) {
    const int t0 = i << 1;
    // ph1: Q(0,0) buf0
    RD_A(0, 0); RD_B(fB0, 0, 0);
    STG(aS0, dA0, t0 + 1, 1);
    SB0(); BAR(); LGK0();
    PRI1(); MM16(0, fB0, 0); PRI0();
    BAR();
    // ph2: Q(0,1) buf0
    RD_B(fB1, 2, 0);
    STG(aS1, dA1, t0 + 1, 1);
    SB0(); BAR(); LGK0();
    PRI1(); MM16(0, fB1, 2); PRI0();
    BAR();
    // ph3: Q(1,0) buf0
    RD_A(4, 0);
    STG(bS0, dB0, t0 + 2, 0);
    SB0(); BAR(); LGK0();
    PRI1(); MM16(4, fB0, 0); PRI0();
    BAR();
    // ph4: Q(1,1) buf0 | gate: buf1 (tile 2i+1) resident
    STG(bS1, dB1, t0 + 2, 0);
    SB0(); BAR();
    PRI1(); MM16(4, fB1, 2); PRI0();
    VMC4();
    BAR();
    // ph5: Q(0,0) buf1
    RD_A(0, 1); RD_B(fB0, 0, 1);
    STG(aS0, dA0, t0 + 2, 0);
    SB0(); BAR(); LGK0();
    PRI1(); MM16(0, fB0, 0); PRI0();
    BAR();
    // ph6: Q(0,1) buf1
    RD_B(fB1, 2, 1);
    STG(aS1, dA1, t0 + 2, 0);
    SB0(); BAR(); LGK0();
    PRI1(); MM16(0, fB1, 2); PRI0();
    BAR();
    // ph7: Q(1,0) buf1
    RD_A(4, 1);
    STG(bS0, dB0, t0 + 3, 1);
    SB0(); BAR(); LGK0();
    PRI1(); MM16(4, fB0, 0); PRI0();
    BAR();
    // ph8: Q(1,1) buf1 | gate: buf0 (tile 2i+2) resident
    STG(bS1, dB1, t0 + 3, 1);
    SB0(); BAR();
    PRI1(); MM16(4, fB1, 2); PRI0();
    VMC4();
    BAR();
  }

  // ---- tail: tiles NT-2 (buf0), NT-1 (buf1); only Ah(NT-1) left to stage
  {
    RD_A(0, 0); RD_B(fB0, 0, 0);
    STG(aS0, dA0, NT - 1, 1);
    SB0(); BAR(); LGK0();
    PRI1(); MM16(0, fB0, 0); PRI0();
    BAR();
    RD_B(fB1, 2, 0);
    STG(aS1, dA1, NT - 1, 1);
    SB0(); BAR(); LGK0();
    PRI1(); MM16(0, fB1, 2); PRI0();
    BAR();
    RD_A(4, 0);
    SB0(); BAR(); LGK0();
    PRI1(); MM16(4, fB0, 0); PRI0();
    BAR();
    BAR();
    PRI1(); MM16(4, fB1, 2); PRI0();
    VMC0();
    BAR();
    RD_A(0, 1); RD_B(fB0, 0, 1);
    SB0(); BAR(); LGK0();
    PRI1(); MM16(0, fB0, 0); PRI0();
    BAR();
    RD_B(fB1, 2, 1);
    SB0(); BAR(); LGK0();
    PRI1(); MM16(0, fB1, 2); PRI0();
    BAR();
    RD_A(4, 1);
    SB0(); BAR(); LGK0();
    PRI1(); MM16(4, fB0, 0); PRI0();
    BAR();
    PRI1(); MM16(4, fB1, 2); PRI0();
  }

  // ---- epilogue: C/D layout col=lan, row=quad*4+e
  float bsv[4];
#pragma unroll
  for (int n = 0; n < 4; ++n) bsv[n] = bias[bn + (wn << 6) + (n << 4) + lan];
#pragma unroll
  for (int m = 0; m < 8; ++m) {
#pragma unroll
    for (int e = 0; e < 4; ++e) {
      const long row = bm + (wm << 7) + (m << 4) + (quad << 2) + e;
#pragma unroll
      for (int n = 0; n < 4; ++n) {
        const float v = acc[m][n][e] + bsv[n];
        const long col = bn + (wn << 6) + (n << 4) + lan;
        if (OUT_F32) ((float*)Cout)[row * N + col] = v;
        else ((__hip_bfloat16*)Cout)[row * N + col] = __float2bfloat16(v);
      }
    }
  }
}
#undef STG
#undef RD_A
#undef RD_B
#undef MM16

// ---------------------------------------------------------------- flash attention (S^T form)
__global__ void __launch_bounds__(256, 2) flash_attn(const __hip_bfloat16* __restrict__ QKV,
                                                     const __hip_bfloat16* __restrict__ VT,
                                                     __hip_bfloat16* __restrict__ Ctx, int S) {
  __shared__ __align__(16) char smem[50176];
  char* Ks = smem;          // 16KB loop: K tile [64][256B] swizzled; preload: Q rows 0..63
  char* Vs = smem + 16384;  // 16KB loop: V^T tile [128][128B] swizzled; preload: Q rows 64..127
  char* Ps = smem + 32768;  // 17408B: P, 8 strips x (16 rows x 136B)
  const int t = threadIdx.x, w = t >> 6, l = t & 63, quad = l >> 4, lan = l & 15;
  const int b = blockIdx.z, qh = blockIdx.y, kvh = qh >> 2;
  const int q0idx = (int)gridDim.x - 1 - blockIdx.x;  // heavy blocks dispatch first
  const int q0 = q0idx << 7;
  const float cl = 0.08838834764831845f * 1.4426950408889634f;  // 1/sqrt(128) * log2(e)

  // ---- preload 128-row Q tile into smem[0..32767], chunk-swizzled (c ^ row&15)
  {
    int rl = l >> 4, cd = l & 15;
#pragma unroll
    for (int ii = 0; ii < 8; ii++) {
      int i = (w << 3) + ii;
      int r = (i << 2) + rl;
      int cs = cd ^ (r & 15);
      const char* g =
          (const char*)(QKV + (long)(b * S + q0 + r) * 6144 + qh * 128) + (cs << 4);
      g2lds16(g, smem + (i << 10));
    }
  }
  __syncthreads();
  // Q fragments (B-operand): strip = 2w+st, row = strip*16+lan, row&15 == lan
  bf16x8 qf[2][4];
#pragma unroll
  for (int st = 0; st < 2; st++) {
    int row = ((((w << 1) + st) << 4) + lan);
#pragma unroll
    for (int ks = 0; ks < 4; ks++)
      qf[st][ks] = *(const bf16x8*)(smem + (row << 8) + ((((ks << 2) + quad) ^ lan) << 4));
  }

  f32x4 o[2][8] = {};
  float m0[2] = {-__builtin_inff(), -__builtin_inff()};
  float lsum[2] = {0.f, 0.f};
  const int ntiles = (q0idx << 1) + 2;

  for (int kt = 0; kt < ntiles; kt++) {
    const int t0 = kt << 6;
    __syncthreads();  // prior-iter LDS reads (and qf preload reads) done
    // stage K tile [64 rows][256B], swizzled
    {
      int rl = l >> 4, cd = l & 15;
#pragma unroll
      for (int ii = 0; ii < 4; ii++) {
        int i = (w << 2) + ii;
        int r = (i << 2) + rl;
        int cs = cd ^ (r & 15);
        const char* g =
            (const char*)(QKV + (long)(b * S + t0 + r) * 6144 + 4096 + kvh * 128) + (cs << 4);
        g2lds16(g, Ks + (i << 10));
      }
      // stage V^T tile [128 rows][128B], swizzled (c ^ d&7)
      int dl = l >> 3, cd2 = l & 7;
#pragma unroll
      for (int ii = 0; ii < 4; ii++) {
        int i = (w << 2) + ii;
        int d = (i << 3) + dl;
        int cs = cd2 ^ dl;
        const char* g =
            (const char*)(VT + ((long)((b << 3) + kvh) * 128 + d) * S + t0) + (cs << 4);
        g2lds16(g, Vs + (i << 10));
      }
    }
    __syncthreads();

    // S^T[t][q] = K·Q^T : 4 j-tiles (t), each K frag feeds both strips
    f32x4 sa[2][4] = {{}, {}};
#pragma unroll
    for (int j = 0; j < 4; j++)
#pragma unroll
      for (int ks = 0; ks < 4; ks++) {
        bf16x8 kf = *(const bf16x8*)(Ks + (((j << 4) + lan) << 8) +
                                     ((((ks << 2) + quad) ^ lan) << 4));
        sa[0][j] = MFMA(kf, qf[0][ks], sa[0][j]);
        sa[1][j] = MFMA(kf, qf[1][ks], sa[1][j]);
      }

#pragma unroll
    for (int st = 0; st < 2; st++) {
      const int strip = (w << 1) + st;
      const int qg = q0 + (strip << 4) + lan;  // this lane's q row (C/D col = lan)
      if (t0 + 63 > q0 + (strip << 4)) {       // causal mask needed on this tile
#pragma unroll
        for (int j = 0; j < 4; j++)
#pragma unroll
          for (int e = 0; e < 4; e++)
            if (t0 + (j << 4) + (quad << 2) + e > qg) sa[st][j][e] = -1e30f;
      }
      // max over t: in-lane (16 vals) + 2 shfl across quads
      float mq = sa[st][0][0];
#pragma unroll
      for (int j = 0; j < 4; j++)
#pragma unroll
        for (int e = 0; e < 4; e++) mq = fmaxf(mq, sa[st][j][e]);
      mq = fmaxf(mq, __shfl_xor(mq, 16));
      mq = fmaxf(mq, __shfl_xor(mq, 32));
      float mn = fmaxf(m0[st], mq);
      float al = exp2f((m0[st] - mn) * cl);
      m0[st] = mn;
      float rs = 0.f;
      char* prow = Ps + strip * 2176 + lan * 136;
#pragma unroll
      for (int j = 0; j < 4; j++) {
        float p0 = exp2f((sa[st][j][0] - mn) * cl);
        float p1 = exp2f((sa[st][j][1] - mn) * cl);
        float p2 = exp2f((sa[st][j][2] - mn) * cl);
        float p3 = exp2f((sa[st][j][3] - mn) * cl);
        rs += (p0 + p1) + (p2 + p3);
        ushort4 u;
        u.x = bfbits(p0); u.y = bfbits(p1); u.z = bfbits(p2); u.w = bfbits(p3);
        *(ushort4*)(prow + (j << 5) + (quad << 3)) = u;  // P[q=lan][t=j*16+quad*4..+3]
      }
      rs += __shfl_xor(rs, 16);
      rs += __shfl_xor(rs, 32);
      lsum[st] = lsum[st] * al + rs;
#pragma unroll
      for (int dt = 0; dt < 8; dt++) o[st][dt] *= al;
    }

    // O^T += V^T · P^T : same-wave LDS write->read (DS ops in-order per wave)
    bf16x8 pf[2][2];
#pragma unroll
    for (int st = 0; st < 2; st++) {
      char* prow = Ps + ((w << 1) + st) * 2176 + lan * 136;
      pf[st][0] = *(const bf16x8*)(prow + (quad << 4));
      pf[st][1] = *(const bf16x8*)(prow + 64 + (quad << 4));
    }
#pragma unroll
    for (int dt = 0; dt < 8; dt++) {
      const int drow = (dt << 4) + lan;
#pragma unroll
      for (int ks = 0; ks < 2; ks++) {
        bf16x8 vf = *(const bf16x8*)(Vs + (drow << 7) +
                                     ((((ks << 2) + quad) ^ (lan & 7)) << 4));
        o[0][dt] = MFMA(vf, pf[0][ks], o[0][dt]);
        o[1][dt] = MFMA(vf, pf[1][ks], o[1][dt]);
      }
    }
  }

  // epilogue: O^T lane holds q = strip*16+lan, d = dt*16+quad*4+e -> packed 8B stores
#pragma unroll
  for (int st = 0; st < 2; st++) {
    float inv = 1.0f / lsum[st];
    int strip = (w << 1) + st;
    long token = (long)b * S + q0 + (strip << 4) + lan;
    __hip_bfloat16* obase = Ctx + token * 4096 + qh * 128;
#pragma unroll
    for (int dt = 0; dt < 8; dt++) {
      ushort4 u;
      u.x = bfbits(o[st][dt][0] * inv);
      u.y = bfbits(o[st][dt][1] * inv);
      u.z = bfbits(o[st][dt][2] * inv);
      u.w = bfbits(o[st][dt][3] * inv);
      *(ushort4*)(obase + (dt << 4) + (quad << 2)) = u;
    }
  }
}

// ---------------------------------------------------------------- launch
extern "C" void kernel_launch(void* const* d_in, const int* in_sizes, int n_in,
                              void* d_out, int out_size, void* d_ws, size_t ws_size,
                              hipStream_t stream) {
  const float* xs = (const float*)d_in[0];
  const int* startpos = (const int*)d_in[1];
  const float* fc = (const float*)d_in[2];
  const float* Wq = (const float*)d_in[3];
  const float* bq = (const float*)d_in[4];
  const float* Wk = (const float*)d_in[5];
  const float* bk = (const float*)d_in[6];
  const float* Wv = (const float*)d_in[7];
  const float* bv = (const float*)d_in[8];
  const float* Wo = (const float*)d_in[9];
  const float* bo = (const float*)d_in[10];
  float* out = (float*)d_out;
  char* ws = (char*)d_ws;

  __hip_bfloat16* Wqkvb = (__hip_bfloat16*)(ws);               // 48MB [6144][4096]
  __hip_bfloat16* Xb    = (__hip_bfloat16*)(ws + 50331648L);   // 32MB [4096][4096]
  __hip_bfloat16* QKVb  = (__hip_bfloat16*)(ws + 83886080L);   // 48MB [4096][6144]
  __hip_bfloat16* VbT   = (__hip_bfloat16*)(ws + 134217728L);  // 8MB  [16][128][2048]
  float*          bqkv  = (float*)(ws + 142606336L);           // 24KB
  __hip_bfloat16* Wob   = Wqkvb;  // reused after QKV GEMM
  __hip_bfloat16* Ctx   = Xb;     // reused after QKV GEMM

  cvt_f32_bf16<<<16384, 256, 0, stream>>>(xs, Xb, 4194304);
  cvt_f32_bf16<<<16384, 256, 0, stream>>>(Wq, Wqkvb, 4194304);
  cvt_f32_bf16<<<4096, 256, 0, stream>>>(Wk, Wqkvb + 16777216L, 1048576);
  cvt_f32_bf16<<<4096, 256, 0, stream>>>(Wv, Wqkvb + 20971520L, 1048576);
  concat_bias<<<24, 256, 0, stream>>>(bq, bk, bv, bqkv);

  gemm256_bt<0><<<dim3(384), 512, 0, stream>>>(Xb, Wqkvb, bqkv, QKVb, 4096, 6144, 4096);

  rope_inplace<<<32768, 256, 0, stream>>>(QKVb, fc, startpos, 6144, 11, 8388608L);
  rope_inplace<<<8192, 256, 0, stream>>>(QKVb + 4096, fc, startpos, 6144, 9, 2097152L);
  transpose_v<<<dim3(64, 4, 16), dim3(32, 8), 0, stream>>>(QKVb, VbT);
  cvt_f32_bf16<<<16384, 256, 0, stream>>>(Wo, Wob, 4194304);  // after QKV GEMM: aliases Wqkvb

  flash_attn<<<dim3(16, 32, 2), 256, 0, stream>>>(QKVb, VbT, Ctx, 2048);

  gemm256_bt<1><<<dim3(256), 512, 0, stream>>>(Ctx, Wob, bo, out, 4096, 4096, 4096);
}

// Round 3
// 808.897 us; speedup vs baseline: 1.2061x; 1.0204x over previous
//
#include <hip/hip_runtime.h>
#include <hip/hip_bf16.h>

typedef __bf16 bf16x8 __attribute__((ext_vector_type(8)));
typedef float  f32x4  __attribute__((ext_vector_type(4)));

#define MFMA(a, b, c) __builtin_amdgcn_mfma_f32_16x16x32_bf16((a), (b), (c), 0, 0, 0)

typedef __attribute__((address_space(1))) void* as1_vp;
typedef __attribute__((address_space(3))) void* as3_vp;

__device__ __forceinline__ void g2lds16(const void* g, void* lds) {
  __builtin_amdgcn_global_load_lds((as1_vp)(unsigned long long)g,
                                   (as3_vp)(unsigned int)(unsigned long long)lds,
                                   16, 0, 0);
}

__device__ __forceinline__ unsigned short bfbits(float x) {
  return __builtin_bit_cast(unsigned short, __float2bfloat16(x));
}

// ---------------------------------------------------------------- convert
__global__ void cvt_f32_bf16(const float* __restrict__ in,
                             __hip_bfloat16* __restrict__ out, int n4) {
  int i = blockIdx.x * blockDim.x + threadIdx.x;
  if (i >= n4) return;
  float4 v = ((const float4*)in)[i];
  ushort4 u;
  u.x = bfbits(v.x); u.y = bfbits(v.y); u.z = bfbits(v.z); u.w = bfbits(v.w);
  ((ushort4*)out)[i] = u;
}

// ---------------------------------------------------------------- bias concat (fp32)
__global__ void concat_bias(const float* __restrict__ bq, const float* __restrict__ bk,
                            const float* __restrict__ bv, float* __restrict__ out) {
  int i = blockIdx.x * 256 + threadIdx.x;  // 6144 total
  float v = (i < 4096) ? bq[i] : ((i < 5120) ? bk[i - 4096] : bv[i - 5120]);
  out[i] = v;
}

// ---------------------------------------------------------------- rope (in-place, pitch-aware)
__global__ void rope_inplace(__hip_bfloat16* __restrict__ x, const float* __restrict__ fc,
                             const int* __restrict__ startpos, int pitch, int wshift,
                             long npairs) {
  long i = (long)blockIdx.x * blockDim.x + threadIdx.x;
  if (i >= npairs) return;
  int  wi    = (int)(i & ((1 << wshift) - 1));
  long token = i >> wshift;
  int  s  = (int)(token & 2047);
  int  j  = wi & 63;
  int  sp = startpos[0] + s;
  float c  = fc[(sp << 7) + (j << 1)];
  float sn = fc[(sp << 7) + (j << 1) + 1];
  long base = token * pitch + wi * 2;
  float xr = __bfloat162float(x[base]);
  float xi = __bfloat162float(x[base + 1]);
  x[base]     = __float2bfloat16(xr * c - xi * sn);
  x[base + 1] = __float2bfloat16(xr * sn + xi * c);
}

// ---------------------------------------------------------------- V transpose
__global__ void transpose_v(const __hip_bfloat16* __restrict__ QKV,
                            __hip_bfloat16* __restrict__ VT) {
  __shared__ __hip_bfloat16 tile[32][33];
  int z = blockIdx.z, b = z >> 3, kvh = z & 7;
  int s0 = blockIdx.x * 32, h0 = blockIdx.y * 32;
  int tx = threadIdx.x, ty = threadIdx.y;
#pragma unroll
  for (int ry = ty; ry < 32; ry += 8)
    tile[ry][tx] =
        QKV[(long)(b * 2048 + s0 + ry) * 6144 + 5120 + kvh * 128 + h0 + tx];
  __syncthreads();
#pragma unroll
  for (int ry = ty; ry < 32; ry += 8)
    VT[((long)z * 128 + h0 + ry) * 2048 + s0 + tx] = tile[tx][ry];
}

// ---------------------------------------------------------------- GEMM  C = A * W^T + bias
// 256x256 tile, BK=64, 512 thr = 8 waves (2M x 4N), 8-phase schedule with
// counted vmcnt (T3+T4), 2-bit LDS chunk swizzle (T2), setprio around MFMA (T5).
// LDS 128KB: [buf(2)][ A: half0 16K | half1 16K | B: half0 16K | half1 16K ]
// Each half-tile = [ksub(2)][128 rows][64B], chunk c stored at c ^ ((row>>1)&3).
#define BAR()  __builtin_amdgcn_s_barrier()
#define SB0()  __builtin_amdgcn_sched_barrier(0)
#define LGK0() do { asm volatile("s_waitcnt lgkmcnt(0)" ::: "memory"); \
                    __builtin_amdgcn_sched_barrier(0); } while (0)
#define VMC8() asm volatile("s_waitcnt vmcnt(8)" ::: "memory")
#define VMC4() asm volatile("s_waitcnt vmcnt(4)" ::: "memory")
#define VMC0() asm volatile("s_waitcnt vmcnt(0)" ::: "memory")
#define PRI1() __builtin_amdgcn_s_setprio(1)
#define PRI0() __builtin_amdgcn_s_setprio(0)

template <int OUT_F32>
__global__ void __launch_bounds__(512, 2)
gemm256_bt(const __hip_bfloat16* __restrict__ A,
           const __hip_bfloat16* __restrict__ W,
           const float* __restrict__ bias,
           void* __restrict__ Cout, int M, int N, int K) {
  __shared__ __align__(16) char smem[131072];
  (void)M;
  const int t = threadIdx.x, w = t >> 6, l = t & 63, quad = l >> 4, lan = l & 15;
  const int wm = w >> 2, wn = w & 3;

  // bijective XCD swizzle (8 XCDs), m204 form
  const int nwg = gridDim.x;
  const int xcd = blockIdx.x & 7, lid = blockIdx.x >> 3;
  const int qq = nwg >> 3, rr = nwg & 7;
  const int wg = (xcd < rr ? xcd * (qq + 1) : rr * (qq + 1) + (xcd - rr) * qq) + lid;
  const int ntn = N >> 8;
  const int bm = (wg / ntn) << 8, bn = (wg % ntn) << 8;

  // ---- staging source pointers (per-thread; chunk pre-swizzled so LDS dest is linear)
  // thread t covers row r=t>>2 (within 128-row half), chunk c=t&3; src chunk = c ^ ((r>>1)&3)
  const int csrc = ((t & 3) ^ ((t >> 3) & 3)) << 4;
  const char* aS0 = (const char*)(A + (long)(bm + (t >> 2)) * K) + csrc;
  const char* aS1 = aS0 + (long)K * 256;  // +128 rows
  const char* bS0 = (const char*)(W + (long)(bn + (t >> 2)) * K) + csrc;
  const char* bS1 = bS0 + (long)K * 256;
  // wave-uniform LDS staging dests (hw appends lane*16)
  char* dA0 = smem + (w << 10);
  char* dA1 = smem + 16384 + (w << 10);
  char* dB0 = smem + 32768 + (w << 10);
  char* dB1 = smem + 49152 + (w << 10);

#define STG(src, dst, kt, bb)                                    \
  g2lds16((src) + (kt) * 128, (dst) + (bb) * 65536);             \
  g2lds16((src) + (kt) * 128 + 64, (dst) + (bb) * 65536 + 8192);

  // ---- fragment read bases (per-lane), same swizzle on read side
  const int rsw = (quad ^ ((lan >> 1) & 3)) << 4;
  const char* aR = smem + wm * 16384 + (lan << 6) + rsw;
  const char* bR = smem + 32768 + (wn >> 1) * 16384 + ((((wn & 1) << 6) + lan) << 6) + rsw;

  f32x4 acc[8][4] = {};
  bf16x8 fA[4][2], fB0[2][2], fB1[2][2];

#define RD_A(mb, bb)                                                          \
  _Pragma("unroll") for (int mm = 0; mm < 4; ++mm)                            \
  _Pragma("unroll") for (int j = 0; j < 2; ++j)                               \
    fA[mm][j] = *(const bf16x8*)(aR + (bb) * 65536 + ((mb) + mm) * 1024 + j * 8192);
#define RD_B(arr, nb, bb)                                                     \
  _Pragma("unroll") for (int nn = 0; nn < 2; ++nn)                            \
  _Pragma("unroll") for (int j = 0; j < 2; ++j)                               \
    arr[nn][j] = *(const bf16x8*)(bR + (bb) * 65536 + ((nb) + nn) * 1024 + j * 8192);
#define MM16(mb, arr, nb)                                                     \
  _Pragma("unroll") for (int mm = 0; mm < 4; ++mm)                            \
  _Pragma("unroll") for (int nn = 0; nn < 2; ++nn)                            \
  _Pragma("unroll") for (int j = 0; j < 2; ++j)                               \
    acc[(mb) + mm][(nb) + nn] = MFMA(fA[mm][j], arr[nn][j], acc[(mb) + mm][(nb) + nn]);

  // ---- prologue: tile0 (buf0) fully, then tile1 B-halves (buf1); keep last 4 loads in flight
  STG(aS0, dA0, 0, 0); STG(aS1, dA1, 0, 0);
  STG(bS0, dB0, 0, 0); STG(bS1, dB1, 0, 0);
  STG(bS0, dB0, 1, 1); STG(bS1, dB1, 1, 1);
  VMC4();
  BAR();

  const int NT = K >> 6;
  // steady state per iter i (tiles 2i in buf0, 2i+1 in buf1):
  //  ph1: Ah0(2i+1)->buf1   ph2: Ah1(2i+1)->buf1   ph3: Bh0(2i+2)->buf0
  //  ph4: Bh1(2i+2)->buf0 +vmcnt(4)                ph5: Ah0(2i+2)->buf0
  //  ph6: Ah1(2i+2)->buf0   ph7: Bh0(2i+3)->buf1   ph8: Bh1(2i+3)->buf1 +vmcnt(4)
  // region-free proof: B reads of a tile finish ph2/ph6 (lgkmcnt0), A reads ph3/ph7.
  for (int i = 0; i < (NT >> 1) - 1; ++i) {
    const int t0 = i << 1;
    // ph1: Q(0,0) buf0
    RD_A(0, 0); RD_B(fB0, 0, 0);
    STG(aS0, dA0, t0 + 1, 1);
    SB0(); BAR(); LGK0();
    PRI1(); MM16(0, fB0, 0); PRI0();
    BAR();
    // ph2: Q(0,1) buf0
    RD_B(fB1, 2, 0);
    STG(aS1, dA1, t0 + 1, 1);
    SB0(); BAR(); LGK0();
    PRI1(); MM16(0, fB1, 2); PRI0();
    BAR();
    // ph3: Q(1,0) buf0
    RD_A(4, 0);
    STG(bS0, dB0, t0 + 2, 0);
    SB0(); BAR(); LGK0();
    PRI1(); MM16(4, fB0, 0); PRI0();
    BAR();
    // ph4: Q(1,1) buf0 | gate: buf1 (tile 2i+1) resident
    STG(bS1, dB1, t0 + 2, 0);
    SB0(); BAR();
    PRI1(); MM16(4, fB1, 2); PRI0();
    VMC4();
    BAR();
    // ph5: Q(0,0) buf1
    RD_A(0, 1); RD_B(fB0, 0, 1);
    STG(aS0, dA0, t0 + 2, 0);
    SB0(); BAR(); LGK0();
    PRI1(); MM16(0, fB0, 0); PRI0();
    BAR();
    // ph6: Q(0,1) buf1
    RD_B(fB1, 2, 1);
    STG(aS1, dA1, t0 + 2, 0);
    SB0(); BAR(); LGK0();
    PRI1(); MM16(0, fB1, 2); PRI0();
    BAR();
    // ph7: Q(1,0) buf1
    RD_A(4, 1);
    STG(bS0, dB0, t0 + 3, 1);
    SB0(); BAR(); LGK0();
    PRI1(); MM16(4, fB0, 0); PRI0();
    BAR();
    // ph8: Q(1,1) buf1 | gate: buf0 (tile 2i+2) resident
    STG(bS1, dB1, t0 + 3, 1);
    SB0(); BAR();
    PRI1(); MM16(4, fB1, 2); PRI0();
    VMC4();
    BAR();
  }

  // ---- tail: tiles NT-2 (buf0), NT-1 (buf1); only Ah(NT-1) left to stage
  {
    RD_A(0, 0); RD_B(fB0, 0, 0);
    STG(aS0, dA0, NT - 1, 1);
    SB0(); BAR(); LGK0();
    PRI1(); MM16(0, fB0, 0); PRI0();
    BAR();
    RD_B(fB1, 2, 0);
    STG(aS1, dA1, NT - 1, 1);
    SB0(); BAR(); LGK0();
    PRI1(); MM16(0, fB1, 2); PRI0();
    BAR();
    RD_A(4, 0);
    SB0(); BAR(); LGK0();
    PRI1(); MM16(4, fB0, 0); PRI0();
    BAR();
    BAR();
    PRI1(); MM16(4, fB1, 2); PRI0();
    VMC0();
    BAR();
    RD_A(0, 1); RD_B(fB0, 0, 1);
    SB0(); BAR(); LGK0();
    PRI1(); MM16(0, fB0, 0); PRI0();
    BAR();
    RD_B(fB1, 2, 1);
    SB0(); BAR(); LGK0();
    PRI1(); MM16(0, fB1, 2); PRI0();
    BAR();
    RD_A(4, 1);
    SB0(); BAR(); LGK0();
    PRI1(); MM16(4, fB0, 0); PRI0();
    BAR();
    PRI1(); MM16(4, fB1, 2); PRI0();
  }

  // ---- epilogue: C/D layout col=lan, row=quad*4+e
  float bsv[4];
#pragma unroll
  for (int n = 0; n < 4; ++n) bsv[n] = bias[bn + (wn << 6) + (n << 4) + lan];
#pragma unroll
  for (int m = 0; m < 8; ++m) {
#pragma unroll
    for (int e = 0; e < 4; ++e) {
      const long row = bm + (wm << 7) + (m << 4) + (quad << 2) + e;
#pragma unroll
      for (int n = 0; n < 4; ++n) {
        const float v = acc[m][n][e] + bsv[n];
        const long col = bn + (wn << 6) + (n << 4) + lan;
        if (OUT_F32) ((float*)Cout)[row * N + col] = v;
        else ((__hip_bfloat16*)Cout)[row * N + col] = __float2bfloat16(v);
      }
    }
  }
}
#undef STG
#undef RD_A
#undef RD_B
#undef MM16

// ---------------------------------------------------------------- flash attention (S^T form)
// QKV: [token][6144] (Q cols 0..4095, K 4096..5119), VT: [(b*8+kvh)][128][2048]
// Ctx: [token][4096]. grid (16, 32, 2), 256 thr (4 waves).
// Pipelined: K double-buffered (counted vmcnt), V staged under QK^T+softmax.
// Per-iter vmcnt ledger (per wave): enter with 4 (K[t]) -> +4 V[t] -> +4 K[t+1] = 12
//  -> vmcnt(8): K[t] resident -> vmcnt(4): V[t] resident -> exit with 4 (K[t+1]).
__global__ void __launch_bounds__(256, 2) flash_attn(const __hip_bfloat16* __restrict__ QKV,
                                                     const __hip_bfloat16* __restrict__ VT,
                                                     __hip_bfloat16* __restrict__ Ctx, int S) {
  __shared__ __align__(16) char smem[66560];
  char* Ks0 = smem;           // 16KB K dbuf 0 [64][256B] swz; preload: Q rows 0..63
  char* Ks1 = smem + 16384;   // 16KB K dbuf 1             ; preload: Q rows 64..127
  char* Vs  = smem + 32768;   // 16KB V^T tile [128][128B] swz
  char* Ps  = smem + 49152;   // 17408B: P, 8 strips x (16 rows x 136B), wave-private
  const int t = threadIdx.x, w = t >> 6, l = t & 63, quad = l >> 4, lan = l & 15;
  const int b = blockIdx.z, qh = blockIdx.y, kvh = qh >> 2;
  const int q0idx = (int)gridDim.x - 1 - blockIdx.x;  // heavy blocks dispatch first
  const int q0 = q0idx << 7;
  const float cl = 0.08838834764831845f * 1.4426950408889634f;  // 1/sqrt(128) * log2(e)

  // ---- preload 128-row Q tile into smem[0..32767], chunk-swizzled (c ^ row&15)
  {
    int rl = l >> 4, cd = l & 15;
#pragma unroll
    for (int ii = 0; ii < 8; ii++) {
      int i = (w << 3) + ii;
      int r = (i << 2) + rl;
      int cs = cd ^ (r & 15);
      const char* g =
          (const char*)(QKV + (long)(b * S + q0 + r) * 6144 + qh * 128) + (cs << 4);
      g2lds16(g, smem + (i << 10));
    }
  }
  __syncthreads();  // full drain: Q resident & visible
  // Q fragments (B-operand): strip = 2w+st, row = strip*16+lan, row&15 == lan
  bf16x8 qf[2][4];
#pragma unroll
  for (int st = 0; st < 2; st++) {
    int row = ((((w << 1) + st) << 4) + lan);
#pragma unroll
    for (int ks = 0; ks < 4; ks++)
      qf[st][ks] = *(const bf16x8*)(smem + (row << 8) + ((((ks << 2) + quad) ^ lan) << 4));
  }
  __syncthreads();  // full drain: qf reads done everywhere; Q region now reusable

  const int ntiles = (q0idx << 1) + 2;

  auto stageK = [&](int kt, char* dst) {
    int rl = l >> 4, cd = l & 15;
#pragma unroll
    for (int ii = 0; ii < 4; ii++) {
      int i = (w << 2) + ii;
      int r = (i << 2) + rl;
      int cs = cd ^ (r & 15);
      const char* g =
          (const char*)(QKV + (long)(b * S + (kt << 6) + r) * 6144 + 4096 + kvh * 128) +
          (cs << 4);
      g2lds16(g, dst + (i << 10));
    }
  };
  auto stageV = [&](int kt) {
    int dl = l >> 3, cd2 = l & 7;
#pragma unroll
    for (int ii = 0; ii < 4; ii++) {
      int i = (w << 2) + ii;
      int d = (i << 3) + dl;
      int cs = cd2 ^ dl;
      const char* g =
          (const char*)(VT + ((long)((b << 3) + kvh) * 128 + d) * S + (kt << 6)) + (cs << 4);
      g2lds16(g, Vs + (i << 10));
    }
  };

  f32x4 o[2][8] = {};
  float m0[2] = {-__builtin_inff(), -__builtin_inff()};
  float lsum[2] = {0.f, 0.f};

  stageK(0, Ks0);  // outstanding: 4

  for (int kt = 0; kt < ntiles; kt++) {
    const int t0 = kt << 6;
    char* Kcur = (kt & 1) ? Ks1 : Ks0;
    char* Knxt = (kt & 1) ? Ks0 : Ks1;
    // barrier #1: all waves done reading Vs (prev PV) and Knxt (QK^T of kt-1)
    SB0(); BAR();
    stageV(kt);                       // outstanding: 8
    const int tn = (kt + 1 < ntiles) ? kt + 1 : kt;
    stageK(tn, Knxt);                 // outstanding: 12
    VMC8();                           // own K[kt] writes done
    SB0(); BAR();                     // K[kt] visible to all waves

    // S^T[t][q] = K·Q^T : 4 j-tiles (t), each K frag feeds both strips
    f32x4 sa[2][4] = {{}, {}};
    PRI1();
#pragma unroll
    for (int j = 0; j < 4; j++)
#pragma unroll
      for (int ks = 0; ks < 4; ks++) {
        bf16x8 kf = *(const bf16x8*)(Kcur + (((j << 4) + lan) << 8) +
                                     ((((ks << 2) + quad) ^ lan) << 4));
        sa[0][j] = MFMA(kf, qf[0][ks], sa[0][j]);
        sa[1][j] = MFMA(kf, qf[1][ks], sa[1][j]);
      }
    PRI0();

#pragma unroll
    for (int st = 0; st < 2; st++) {
      const int strip = (w << 1) + st;
      const int qg = q0 + (strip << 4) + lan;  // this lane's q row (C/D col = lan)
      if (t0 + 63 > q0 + (strip << 4)) {       // causal mask needed on this tile
#pragma unroll
        for (int j = 0; j < 4; j++)
#pragma unroll
          for (int e = 0; e < 4; e++)
            if (t0 + (j << 4) + (quad << 2) + e > qg) sa[st][j][e] = -1e30f;
      }
      // max over t: in-lane (16 vals) + 2 shfl across quads
      float mq = sa[st][0][0];
#pragma unroll
      for (int j = 0; j < 4; j++)
#pragma unroll
        for (int e = 0; e < 4; e++) mq = fmaxf(mq, sa[st][j][e]);
      mq = fmaxf(mq, __shfl_xor(mq, 16));
      mq = fmaxf(mq, __shfl_xor(mq, 32));
      float mn = fmaxf(m0[st], mq);
      float al = exp2f((m0[st] - mn) * cl);
      m0[st] = mn;
      float rs = 0.f;
      char* prow = Ps + strip * 2176 + lan * 136;
#pragma unroll
      for (int j = 0; j < 4; j++) {
        float p0 = exp2f((sa[st][j][0] - mn) * cl);
        float p1 = exp2f((sa[st][j][1] - mn) * cl);
        float p2 = exp2f((sa[st][j][2] - mn) * cl);
        float p3 = exp2f((sa[st][j][3] - mn) * cl);
        rs += (p0 + p1) + (p2 + p3);
        ushort4 u;
        u.x = bfbits(p0); u.y = bfbits(p1); u.z = bfbits(p2); u.w = bfbits(p3);
        *(ushort4*)(prow + (j << 5) + (quad << 3)) = u;  // P[q=lan][t=j*16+quad*4..+3]
      }
      rs += __shfl_xor(rs, 16);
      rs += __shfl_xor(rs, 32);
      lsum[st] = lsum[st] * al + rs;
#pragma unroll
      for (int dt = 0; dt < 8; dt++) o[st][dt] *= al;
    }

    // P fragments: same-wave LDS write->read (DS ops in-order per wave)
    bf16x8 pf[2][2];
#pragma unroll
    for (int st = 0; st < 2; st++) {
      char* prow = Ps + ((w << 1) + st) * 2176 + lan * 136;
      pf[st][0] = *(const bf16x8*)(prow + (quad << 4));
      pf[st][1] = *(const bf16x8*)(prow + 64 + (quad << 4));
    }

    VMC4();        // own V[kt] writes done; K[tn] still in flight
    SB0(); BAR();  // V[kt] visible to all waves

    // O^T += V^T · P^T
    PRI1();
#pragma unroll
    for (int dt = 0; dt < 8; dt++) {
      const int drow = (dt << 4) + lan;
#pragma unroll
      for (int ks = 0; ks < 2; ks++) {
        bf16x8 vf = *(const bf16x8*)(Vs + (drow << 7) +
                                     ((((ks << 2) + quad) ^ (lan & 7)) << 4));
        o[0][dt] = MFMA(vf, pf[0][ks], o[0][dt]);
        o[1][dt] = MFMA(vf, pf[1][ks], o[1][dt]);
      }
    }
    PRI0();
  }

  // epilogue: O^T lane holds q = strip*16+lan, d = dt*16+quad*4+e -> packed 8B stores
#pragma unroll
  for (int st = 0; st < 2; st++) {
    float inv = 1.0f / lsum[st];
    int strip = (w << 1) + st;
    long token = (long)b * S + q0 + (strip << 4) + lan;
    __hip_bfloat16* obase = Ctx + token * 4096 + qh * 128;
#pragma unroll
    for (int dt = 0; dt < 8; dt++) {
      ushort4 u;
      u.x = bfbits(o[st][dt][0] * inv);
      u.y = bfbits(o[st][dt][1] * inv);
      u.z = bfbits(o[st][dt][2] * inv);
      u.w = bfbits(o[st][dt][3] * inv);
      *(ushort4*)(obase + (dt << 4) + (quad << 2)) = u;
    }
  }
}

// ---------------------------------------------------------------- launch
extern "C" void kernel_launch(void* const* d_in, const int* in_sizes, int n_in,
                              void* d_out, int out_size, void* d_ws, size_t ws_size,
                              hipStream_t stream) {
  const float* xs = (const float*)d_in[0];
  const int* startpos = (const int*)d_in[1];
  const float* fc = (const float*)d_in[2];
  const float* Wq = (const float*)d_in[3];
  const float* bq = (const float*)d_in[4];
  const float* Wk = (const float*)d_in[5];
  const float* bk = (const float*)d_in[6];
  const float* Wv = (const float*)d_in[7];
  const float* bv = (const float*)d_in[8];
  const float* Wo = (const float*)d_in[9];
  const float* bo = (const float*)d_in[10];
  float* out = (float*)d_out;
  char* ws = (char*)d_ws;

  __hip_bfloat16* Wqkvb = (__hip_bfloat16*)(ws);               // 48MB [6144][4096]
  __hip_bfloat16* Xb    = (__hip_bfloat16*)(ws + 50331648L);   // 32MB [4096][4096]
  __hip_bfloat16* QKVb  = (__hip_bfloat16*)(ws + 83886080L);   // 48MB [4096][6144]
  __hip_bfloat16* VbT   = (__hip_bfloat16*)(ws + 134217728L);  // 8MB  [16][128][2048]
  float*          bqkv  = (float*)(ws + 142606336L);           // 24KB
  __hip_bfloat16* Wob   = Wqkvb;  // reused after QKV GEMM
  __hip_bfloat16* Ctx   = Xb;     // reused after QKV GEMM

  cvt_f32_bf16<<<16384, 256, 0, stream>>>(xs, Xb, 4194304);
  cvt_f32_bf16<<<16384, 256, 0, stream>>>(Wq, Wqkvb, 4194304);
  cvt_f32_bf16<<<4096, 256, 0, stream>>>(Wk, Wqkvb + 16777216L, 1048576);
  cvt_f32_bf16<<<4096, 256, 0, stream>>>(Wv, Wqkvb + 20971520L, 1048576);
  concat_bias<<<24, 256, 0, stream>>>(bq, bk, bv, bqkv);

  gemm256_bt<0><<<dim3(384), 512, 0, stream>>>(Xb, Wqkvb, bqkv, QKVb, 4096, 6144, 4096);

  rope_inplace<<<32768, 256, 0, stream>>>(QKVb, fc, startpos, 6144, 11, 8388608L);
  rope_inplace<<<8192, 256, 0, stream>>>(QKVb + 4096, fc, startpos, 6144, 9, 2097152L);
  transpose_v<<<dim3(64, 4, 16), dim3(32, 8), 0, stream>>>(QKVb, VbT);
  cvt_f32_bf16<<<16384, 256, 0, stream>>>(Wo, Wob, 4194304);  // after QKV GEMM: aliases Wqkvb

  flash_attn<<<dim3(16, 32, 2), 256, 0, stream>>>(QKVb, VbT, Ctx, 2048);

  gemm256_bt<1><<<dim3(256), 512, 0, stream>>>(Ctx, Wob, bo, out, 4096, 4096, 4096);
}

// Round 4
// 778.984 us; speedup vs baseline: 1.2524x; 1.0384x over previous
//
#include <hip/hip_runtime.h>
#include <hip/hip_bf16.h>

typedef __bf16 bf16x8 __attribute__((ext_vector_type(8)));
typedef float  f32x4  __attribute__((ext_vector_type(4)));
typedef short  s16x4  __attribute__((ext_vector_type(4)));

#define MFMA(a, b, c) __builtin_amdgcn_mfma_f32_16x16x32_bf16((a), (b), (c), 0, 0, 0)
#define MFMA16(a, b, c) __builtin_amdgcn_mfma_f32_16x16x16bf16_1k((a), (b), (c), 0, 0, 0)

typedef __attribute__((address_space(1))) void* as1_vp;
typedef __attribute__((address_space(3))) void* as3_vp;

__device__ __forceinline__ void g2lds16(const void* g, void* lds) {
  __builtin_amdgcn_global_load_lds((as1_vp)(unsigned long long)g,
                                   (as3_vp)(unsigned int)(unsigned long long)lds,
                                   16, 0, 0);
}

__device__ __forceinline__ unsigned short bfbits(float x) {
  return __builtin_bit_cast(unsigned short, __float2bfloat16(x));
}

// packed f32x2 -> bf16x2 (RNE), one instruction
__device__ __forceinline__ unsigned cvtpk(float a, float b) {
  unsigned r;
  asm("v_cvt_pk_bf16_f32 %0, %1, %2" : "=v"(r) : "v"(a), "v"(b));
  return r;
}

// ---------------------------------------------------------------- convert
__global__ void cvt_f32_bf16(const float* __restrict__ in,
                             __hip_bfloat16* __restrict__ out, int n4) {
  int i = blockIdx.x * blockDim.x + threadIdx.x;
  if (i >= n4) return;
  float4 v = ((const float4*)in)[i];
  uint2 u;
  u.x = cvtpk(v.x, v.y);
  u.y = cvtpk(v.z, v.w);
  ((uint2*)out)[i] = u;
}

// ---------------------------------------------------------------- bias concat (fp32)
__global__ void concat_bias(const float* __restrict__ bq, const float* __restrict__ bk,
                            const float* __restrict__ bv, float* __restrict__ out) {
  int i = blockIdx.x * 256 + threadIdx.x;  // 6144 total
  float v = (i < 4096) ? bq[i] : ((i < 5120) ? bk[i - 4096] : bv[i - 5120]);
  out[i] = v;
}

// ---------------------------------------------------------------- rope (in-place, pitch-aware)
__global__ void rope_inplace(__hip_bfloat16* __restrict__ x, const float* __restrict__ fc,
                             const int* __restrict__ startpos, int pitch, int wshift,
                             long npairs) {
  long i = (long)blockIdx.x * blockDim.x + threadIdx.x;
  if (i >= npairs) return;
  int  wi    = (int)(i & ((1 << wshift) - 1));
  long token = i >> wshift;
  int  s  = (int)(token & 2047);
  int  j  = wi & 63;
  int  sp = startpos[0] + s;
  float c  = fc[(sp << 7) + (j << 1)];
  float sn = fc[(sp << 7) + (j << 1) + 1];
  long base = token * pitch + wi * 2;
  float xr = __bfloat162float(x[base]);
  float xi = __bfloat162float(x[base + 1]);
  x[base]     = __float2bfloat16(xr * c - xi * sn);
  x[base + 1] = __float2bfloat16(xr * sn + xi * c);
}

// ---------------------------------------------------------------- V transpose
// Writes VT[d][t ^ (((d>>3)&1)*4)] -- 8B half-swap per 16B chunk keyed on d bit3,
// paired with flash_attn's PV read (both-sides swizzle) to keep b64 reads 2-way.
__global__ void transpose_v(const __hip_bfloat16* __restrict__ QKV,
                            __hip_bfloat16* __restrict__ VT) {
  __shared__ __hip_bfloat16 tile[32][33];
  int z = blockIdx.z, b = z >> 3, kvh = z & 7;
  int s0 = blockIdx.x * 32, h0 = blockIdx.y * 32;
  int tx = threadIdx.x, ty = threadIdx.y;
#pragma unroll
  for (int ry = ty; ry < 32; ry += 8)
    tile[ry][tx] =
        QKV[(long)(b * 2048 + s0 + ry) * 6144 + 5120 + kvh * 128 + h0 + tx];
  __syncthreads();
#pragma unroll
  for (int ry = ty; ry < 32; ry += 8) {
    int dd = h0 + ry;
    int tc = (s0 + tx) ^ (((dd >> 3) & 1) << 2);
    VT[((long)z * 128 + dd) * 2048 + tc] = tile[tx][ry];
  }
}

// ---------------------------------------------------------------- GEMM  C = A * W^T + bias
// 256x256 tile, BK=64, 512 thr = 8 waves (2M x 4N), 8-phase schedule with
// counted vmcnt (T3+T4), 2-bit LDS chunk swizzle (T2), setprio around MFMA (T5).
#define BAR()  __builtin_amdgcn_s_barrier()
#define SB0()  __builtin_amdgcn_sched_barrier(0)
#define LGK0() do { asm volatile("s_waitcnt lgkmcnt(0)" ::: "memory"); \
                    __builtin_amdgcn_sched_barrier(0); } while (0)
#define VMC8() asm volatile("s_waitcnt vmcnt(8)" ::: "memory")
#define VMC4() asm volatile("s_waitcnt vmcnt(4)" ::: "memory")
#define VMC0() asm volatile("s_waitcnt vmcnt(0)" ::: "memory")
#define PRI1() __builtin_amdgcn_s_setprio(1)
#define PRI0() __builtin_amdgcn_s_setprio(0)

template <int OUT_F32>
__global__ void __launch_bounds__(512, 2)
gemm256_bt(const __hip_bfloat16* __restrict__ A,
           const __hip_bfloat16* __restrict__ W,
           const float* __restrict__ bias,
           void* __restrict__ Cout, int M, int N, int K) {
  __shared__ __align__(16) char smem[131072];
  (void)M;
  const int t = threadIdx.x, w = t >> 6, l = t & 63, quad = l >> 4, lan = l & 15;
  const int wm = w >> 2, wn = w & 3;

  const int nwg = gridDim.x;
  const int xcd = blockIdx.x & 7, lid = blockIdx.x >> 3;
  const int qq = nwg >> 3, rr = nwg & 7;
  const int wg = (xcd < rr ? xcd * (qq + 1) : rr * (qq + 1) + (xcd - rr) * qq) + lid;
  const int ntn = N >> 8;
  const int bm = (wg / ntn) << 8, bn = (wg % ntn) << 8;

  const int csrc = ((t & 3) ^ ((t >> 3) & 3)) << 4;
  const char* aS0 = (const char*)(A + (long)(bm + (t >> 2)) * K) + csrc;
  const char* aS1 = aS0 + (long)K * 256;
  const char* bS0 = (const char*)(W + (long)(bn + (t >> 2)) * K) + csrc;
  const char* bS1 = bS0 + (long)K * 256;
  char* dA0 = smem + (w << 10);
  char* dA1 = smem + 16384 + (w << 10);
  char* dB0 = smem + 32768 + (w << 10);
  char* dB1 = smem + 49152 + (w << 10);

#define STG(src, dst, kt, bb)                                    \
  g2lds16((src) + (kt) * 128, (dst) + (bb) * 65536);             \
  g2lds16((src) + (kt) * 128 + 64, (dst) + (bb) * 65536 + 8192);

  const int rsw = (quad ^ ((lan >> 1) & 3)) << 4;
  const char* aR = smem + wm * 16384 + (lan << 6) + rsw;
  const char* bR = smem + 32768 + (wn >> 1) * 16384 + ((((wn & 1) << 6) + lan) << 6) + rsw;

  f32x4 acc[8][4] = {};
  bf16x8 fA[4][2], fB0[2][2], fB1[2][2];

#define RD_A(mb, bb)                                                          \
  _Pragma("unroll") for (int mm = 0; mm < 4; ++mm)                            \
  _Pragma("unroll") for (int j = 0; j < 2; ++j)                               \
    fA[mm][j] = *(const bf16x8*)(aR + (bb) * 65536 + ((mb) + mm) * 1024 + j * 8192);
#define RD_B(arr, nb, bb)                                                     \
  _Pragma("unroll") for (int nn = 0; nn < 2; ++nn)                            \
  _Pragma("unroll") for (int j = 0; j < 2; ++j)                               \
    arr[nn][j] = *(const bf16x8*)(bR + (bb) * 65536 + ((nb) + nn) * 1024 + j * 8192);
#define MM16(mb, arr, nb)                                                     \
  _Pragma("unroll") for (int mm = 0; mm < 4; ++mm)                            \
  _Pragma("unroll") for (int nn = 0; nn < 2; ++nn)                            \
  _Pragma("unroll") for (int j = 0; j < 2; ++j)                               \
    acc[(mb) + mm][(nb) + nn] = MFMA(fA[mm][j], arr[nn][j], acc[(mb) + mm][(nb) + nn]);

  STG(aS0, dA0, 0, 0); STG(aS1, dA1, 0, 0);
  STG(bS0, dB0, 0, 0); STG(bS1, dB1, 0, 0);
  STG(bS0, dB0, 1, 1); STG(bS1, dB1, 1, 1);
  VMC4();
  BAR();

  const int NT = K >> 6;
  for (int i = 0; i < (NT >> 1) - 1; ++i) {
    const int t0 = i << 1;
    RD_A(0, 0); RD_B(fB0, 0, 0);
    STG(aS0, dA0, t0 + 1, 1);
    SB0(); BAR(); LGK0();
    PRI1(); MM16(0, fB0, 0); PRI0();
    BAR();
    RD_B(fB1, 2, 0);
    STG(aS1, dA1, t0 + 1, 1);
    SB0(); BAR(); LGK0();
    PRI1(); MM16(0, fB1, 2); PRI0();
    BAR();
    RD_A(4, 0);
    STG(bS0, dB0, t0 + 2, 0);
    SB0(); BAR(); LGK0();
    PRI1(); MM16(4, fB0, 0); PRI0();
    BAR();
    STG(bS1, dB1, t0 + 2, 0);
    SB0(); BAR();
    PRI1(); MM16(4, fB1, 2); PRI0();
    VMC4();
    BAR();
    RD_A(0, 1); RD_B(fB0, 0, 1);
    STG(aS0, dA0, t0 + 2, 0);
    SB0(); BAR(); LGK0();
    PRI1(); MM16(0, fB0, 0); PRI0();
    BAR();
    RD_B(fB1, 2, 1);
    STG(aS1, dA1, t0 + 2, 0);
    SB0(); BAR(); LGK0();
    PRI1(); MM16(0, fB1, 2); PRI0();
    BAR();
    RD_A(4, 1);
    STG(bS0, dB0, t0 + 3, 1);
    SB0(); BAR(); LGK0();
    PRI1(); MM16(4, fB0, 0); PRI0();
    BAR();
    STG(bS1, dB1, t0 + 3, 1);
    SB0(); BAR();
    PRI1(); MM16(4, fB1, 2); PRI0();
    VMC4();
    BAR();
  }

  {
    RD_A(0, 0); RD_B(fB0, 0, 0);
    STG(aS0, dA0, NT - 1, 1);
    SB0(); BAR(); LGK0();
    PRI1(); MM16(0, fB0, 0); PRI0();
    BAR();
    RD_B(fB1, 2, 0);
    STG(aS1, dA1, NT - 1, 1);
    SB0(); BAR(); LGK0();
    PRI1(); MM16(0, fB1, 2); PRI0();
    BAR();
    RD_A(4, 0);
    SB0(); BAR(); LGK0();
    PRI1(); MM16(4, fB0, 0); PRI0();
    BAR();
    BAR();
    PRI1(); MM16(4, fB1, 2); PRI0();
    VMC0();
    BAR();
    RD_A(0, 1); RD_B(fB0, 0, 1);
    SB0(); BAR(); LGK0();
    PRI1(); MM16(0, fB0, 0); PRI0();
    BAR();
    RD_B(fB1, 2, 1);
    SB0(); BAR(); LGK0();
    PRI1(); MM16(0, fB1, 2); PRI0();
    BAR();
    RD_A(4, 1);
    SB0(); BAR(); LGK0();
    PRI1(); MM16(4, fB0, 0); PRI0();
    BAR();
    PRI1(); MM16(4, fB1, 2); PRI0();
  }

  float bsv[4];
#pragma unroll
  for (int n = 0; n < 4; ++n) bsv[n] = bias[bn + (wn << 6) + (n << 4) + lan];
#pragma unroll
  for (int m = 0; m < 8; ++m) {
#pragma unroll
    for (int e = 0; e < 4; ++e) {
      const long row = bm + (wm << 7) + (m << 4) + (quad << 2) + e;
#pragma unroll
      for (int n = 0; n < 4; ++n) {
        const float v = acc[m][n][e] + bsv[n];
        const long col = bn + (wn << 6) + (n << 4) + lan;
        if (OUT_F32) ((float*)Cout)[row * N + col] = v;
        else ((__hip_bfloat16*)Cout)[row * N + col] = __float2bfloat16(v);
      }
    }
  }
}
#undef STG
#undef RD_A
#undef RD_B
#undef MM16

// ---------------------------------------------------------------- flash attention (S^T form)
// QKV: [token][6144] (Q 0..4095, K 4096..5119), VT: [(b*8+kvh)][128][2048] (8B-halfswap by d bit3)
// Ctx: [token][4096]. grid (16, 32, 2), 256 thr (4 waves).
// K double-buffered (counted vmcnt), V staged under QK^T+softmax.
// Softmax fully in-register: P converts via cvt_pk and feeds PV as the B-operand of
// mfma 16x16x16 (B layout col=lan&15, k=quad*4+e == QK^T C/D layout). No P LDS.
// Defer-max: skip rescale unless any lane's tile-max exceeds m0 + 62 (exp2 headroom 7.9).
__global__ void __launch_bounds__(256, 2) flash_attn(const __hip_bfloat16* __restrict__ QKV,
                                                     const __hip_bfloat16* __restrict__ VT,
                                                     __hip_bfloat16* __restrict__ Ctx, int S) {
  __shared__ __align__(16) char smem[49152];
  char* Ks0 = smem;           // 16KB K dbuf 0 [64][256B] swz; preload: Q rows 0..63
  char* Ks1 = smem + 16384;   // 16KB K dbuf 1             ; preload: Q rows 64..127
  char* Vs  = smem + 32768;   // 16KB V^T tile [128][128B] swz
  const int t = threadIdx.x, w = t >> 6, l = t & 63, quad = l >> 4, lan = l & 15;
  const int b = blockIdx.z, qh = blockIdx.y, kvh = qh >> 2;
  const int q0idx = (int)gridDim.x - 1 - blockIdx.x;  // heavy blocks dispatch first
  const int q0 = q0idx << 7;
  const float cl = 0.08838834764831845f * 1.4426950408889634f;  // 1/sqrt(128) * log2(e)

  // ---- preload 128-row Q tile into smem[0..32767], chunk-swizzled (c ^ row&15)
  {
    int rl = l >> 4, cd = l & 15;
#pragma unroll
    for (int ii = 0; ii < 8; ii++) {
      int i = (w << 3) + ii;
      int r = (i << 2) + rl;
      int cs = cd ^ (r & 15);
      const char* g =
          (const char*)(QKV + (long)(b * S + q0 + r) * 6144 + qh * 128) + (cs << 4);
      g2lds16(g, smem + (i << 10));
    }
  }
  __syncthreads();  // full drain: Q resident & visible
  bf16x8 qf[2][4];
#pragma unroll
  for (int st = 0; st < 2; st++) {
    int row = ((((w << 1) + st) << 4) + lan);
#pragma unroll
    for (int ks = 0; ks < 4; ks++)
      qf[st][ks] = *(const bf16x8*)(smem + (row << 8) + ((((ks << 2) + quad) ^ lan) << 4));
  }
  __syncthreads();  // qf reads done everywhere; Q region now reusable

  const int ntiles = (q0idx << 1) + 2;

  auto stageK = [&](int kt, char* dst) {
    int rl = l >> 4, cd = l & 15;
#pragma unroll
    for (int ii = 0; ii < 4; ii++) {
      int i = (w << 2) + ii;
      int r = (i << 2) + rl;
      int cs = cd ^ (r & 15);
      const char* g =
          (const char*)(QKV + (long)(b * S + (kt << 6) + r) * 6144 + 4096 + kvh * 128) +
          (cs << 4);
      g2lds16(g, dst + (i << 10));
    }
  };
  auto stageV = [&](int kt) {
    int dl = l >> 3, cd2 = l & 7;
#pragma unroll
    for (int ii = 0; ii < 4; ii++) {
      int i = (w << 2) + ii;
      int d = (i << 3) + dl;
      int cs = cd2 ^ dl;
      const char* g =
          (const char*)(VT + ((long)((b << 3) + kvh) * 128 + d) * S + (kt << 6)) + (cs << 4);
      g2lds16(g, Vs + (i << 10));
    }
  };

  f32x4 o[2][8] = {};
  float m0[2] = {-__builtin_inff(), -__builtin_inff()};
  float lsum[2] = {0.f, 0.f};

  // PV read constants: chunk xor key = drow&7 = lan&7; 8B half = (quad&1)^((drow>>3)&1)
  const int l7 = lan & 7;
  const int hb = (quad & 1) ^ ((lan >> 3) & 1);

  stageK(0, Ks0);  // outstanding: 4

  for (int kt = 0; kt < ntiles; kt++) {
    const int t0 = kt << 6;
    char* Kcur = (kt & 1) ? Ks1 : Ks0;
    char* Knxt = (kt & 1) ? Ks0 : Ks1;
    SB0(); BAR();  // all waves done reading Vs (prev PV) and Knxt (QK^T of kt-1)
    stageV(kt);                       // outstanding: 8
    const int tn = (kt + 1 < ntiles) ? kt + 1 : kt;
    stageK(tn, Knxt);                 // outstanding: 12
    VMC8();                           // own K[kt] writes done
    SB0(); BAR();                     // K[kt] visible to all waves

    // S^T[t][q] = K·Q^T
    f32x4 sa[2][4] = {{}, {}};
    PRI1();
#pragma unroll
    for (int j = 0; j < 4; j++)
#pragma unroll
      for (int ks = 0; ks < 4; ks++) {
        bf16x8 kf = *(const bf16x8*)(Kcur + (((j << 4) + lan) << 8) +
                                     ((((ks << 2) + quad) ^ lan) << 4));
        sa[0][j] = MFMA(kf, qf[0][ks], sa[0][j]);
        sa[1][j] = MFMA(kf, qf[1][ks], sa[1][j]);
      }
    PRI0();

    s16x4 pb[2][4];
#pragma unroll
    for (int st = 0; st < 2; st++) {
      const int strip = (w << 1) + st;
      const int qg = q0 + (strip << 4) + lan;  // this lane's q row (C/D col = lan)
      if (t0 + 63 > q0 + (strip << 4)) {       // causal mask needed on this tile
#pragma unroll
        for (int j = 0; j < 4; j++)
#pragma unroll
          for (int e = 0; e < 4; e++)
            if (t0 + (j << 4) + (quad << 2) + e > qg) sa[st][j][e] = -1e30f;
      }
      float mq = sa[st][0][0];
#pragma unroll
      for (int j = 0; j < 4; j++)
#pragma unroll
        for (int e = 0; e < 4; e++) mq = fmaxf(mq, sa[st][j][e]);
      mq = fmaxf(mq, __shfl_xor(mq, 16));
      mq = fmaxf(mq, __shfl_xor(mq, 32));
      // defer-max: only rescale when headroom (62 logits = 7.9 in exp2 domain) exceeded
      if (__any(mq > m0[st] + 62.0f)) {
        float mn = fmaxf(m0[st], mq);
        float al = exp2f((m0[st] - mn) * cl);
        m0[st] = mn;
        lsum[st] *= al;
#pragma unroll
        for (int dt = 0; dt < 8; dt++) o[st][dt] *= al;
      }
      float nm = -m0[st] * cl;
      float rs = 0.f;
#pragma unroll
      for (int j = 0; j < 4; j++) {
        float p0 = exp2f(fmaf(sa[st][j][0], cl, nm));
        float p1 = exp2f(fmaf(sa[st][j][1], cl, nm));
        float p2 = exp2f(fmaf(sa[st][j][2], cl, nm));
        float p3 = exp2f(fmaf(sa[st][j][3], cl, nm));
        rs += (p0 + p1) + (p2 + p3);
        uint2 up;
        up.x = cvtpk(p0, p1);
        up.y = cvtpk(p2, p3);
        pb[st][j] = __builtin_bit_cast(s16x4, up);  // B-frag: col=lan&15=q, k=quad*4+e=t
      }
      rs += __shfl_xor(rs, 16);
      rs += __shfl_xor(rs, 32);
      lsum[st] += rs;
    }

    VMC4();        // own V[kt] writes done; K[tn] still in flight
    SB0(); BAR();  // V[kt] visible to all waves

    // O^T += V^T · P^T via 16x16x16 MFMA (A = V^T rows, k=quad*4+e -> 8B reads)
    PRI1();
#pragma unroll
    for (int dt = 0; dt < 8; dt++) {
      const int drow = (dt << 4) + lan;
      const char* vbase = Vs + (drow << 7) + (hb << 3);
#pragma unroll
      for (int j = 0; j < 4; j++) {
        s16x4 vf = *(const s16x4*)(vbase + ((((j << 1) + (quad >> 1)) ^ l7) << 4));
        o[0][dt] = MFMA16(vf, pb[0][j], o[0][dt]);
        o[1][dt] = MFMA16(vf, pb[1][j], o[1][dt]);
      }
    }
    PRI0();
  }

  // epilogue: O^T lane holds q = strip*16+lan, d = dt*16+quad*4+e -> packed 8B stores
#pragma unroll
  for (int st = 0; st < 2; st++) {
    float inv = 1.0f / lsum[st];
    int strip = (w << 1) + st;
    long token = (long)b * S + q0 + (strip << 4) + lan;
    __hip_bfloat16* obase = Ctx + token * 4096 + qh * 128;
#pragma unroll
    for (int dt = 0; dt < 8; dt++) {
      uint2 u;
      u.x = cvtpk(o[st][dt][0] * inv, o[st][dt][1] * inv);
      u.y = cvtpk(o[st][dt][2] * inv, o[st][dt][3] * inv);
      *(uint2*)(obase + (dt << 4) + (quad << 2)) = u;
    }
  }
}

// ---------------------------------------------------------------- launch
extern "C" void kernel_launch(void* const* d_in, const int* in_sizes, int n_in,
                              void* d_out, int out_size, void* d_ws, size_t ws_size,
                              hipStream_t stream) {
  const float* xs = (const float*)d_in[0];
  const int* startpos = (const int*)d_in[1];
  const float* fc = (const float*)d_in[2];
  const float* Wq = (const float*)d_in[3];
  const float* bq = (const float*)d_in[4];
  const float* Wk = (const float*)d_in[5];
  const float* bk = (const float*)d_in[6];
  const float* Wv = (const float*)d_in[7];
  const float* bv = (const float*)d_in[8];
  const float* Wo = (const float*)d_in[9];
  const float* bo = (const float*)d_in[10];
  float* out = (float*)d_out;
  char* ws = (char*)d_ws;

  __hip_bfloat16* Wqkvb = (__hip_bfloat16*)(ws);               // 48MB [6144][4096]
  __hip_bfloat16* Xb    = (__hip_bfloat16*)(ws + 50331648L);   // 32MB [4096][4096]
  __hip_bfloat16* QKVb  = (__hip_bfloat16*)(ws + 83886080L);   // 48MB [4096][6144]
  __hip_bfloat16* VbT   = (__hip_bfloat16*)(ws + 134217728L);  // 8MB  [16][128][2048]
  float*          bqkv  = (float*)(ws + 142606336L);           // 24KB
  __hip_bfloat16* Wob   = Wqkvb;  // reused after QKV GEMM
  __hip_bfloat16* Ctx   = Xb;     // reused after QKV GEMM

  cvt_f32_bf16<<<16384, 256, 0, stream>>>(xs, Xb, 4194304);
  cvt_f32_bf16<<<16384, 256, 0, stream>>>(Wq, Wqkvb, 4194304);
  cvt_f32_bf16<<<4096, 256, 0, stream>>>(Wk, Wqkvb + 16777216L, 1048576);
  cvt_f32_bf16<<<4096, 256, 0, stream>>>(Wv, Wqkvb + 20971520L, 1048576);
  concat_bias<<<24, 256, 0, stream>>>(bq, bk, bv, bqkv);

  gemm256_bt<0><<<dim3(384), 512, 0, stream>>>(Xb, Wqkvb, bqkv, QKVb, 4096, 6144, 4096);

  rope_inplace<<<32768, 256, 0, stream>>>(QKVb, fc, startpos, 6144, 11, 8388608L);
  rope_inplace<<<8192, 256, 0, stream>>>(QKVb + 4096, fc, startpos, 6144, 9, 2097152L);
  transpose_v<<<dim3(64, 4, 16), dim3(32, 8), 0, stream>>>(QKVb, VbT);
  cvt_f32_bf16<<<16384, 256, 0, stream>>>(Wo, Wob, 4194304);  // after QKV GEMM: aliases Wqkvb

  flash_attn<<<dim3(16, 32, 2), 256, 0, stream>>>(QKVb, VbT, Ctx, 2048);

  gemm256_bt<1><<<dim3(256), 512, 0, stream>>>(Ctx, Wob, bo, out, 4096, 4096, 4096);
}